// Round 4
// baseline (533.576 us; speedup 1.0000x reference)
//
#include <hip/hip_runtime.h>
#include <math.h>

#define DDIM 256
#define TILE_CODES 32
#define TILE_BYTES 16384     // 32 codes x 256 dims x 2B (panel layout)
#define NTILES 64            // K=2048 / 32
#define ROWS_PER_BLOCK 32    // one 32-row z panel per block, full K per block

typedef __attribute__((ext_vector_type(8))) short short8v;
typedef __attribute__((ext_vector_type(4))) float float4v;
typedef unsigned int u32;
typedef unsigned short u16;

// ---- RNE float -> bf16 ----
__device__ __forceinline__ short f2bf(float x) {
    u32 u = __float_as_uint(x);
    u = u + 0x7fffu + ((u >> 16) & 1u);
    return (short)(u >> 16);
}

// ---- numpy pairwise-sum simulation (bit-faithful for n=256 contiguous) ----
__device__ __forceinline__ float np_sq_chain(const float* v, int lane) {
    #pragma clang fp contract(off)
    const int half = lane >> 3, j = lane & 7;
    const float* base = v + half * 128 + j;
    float x = base[0];
    float c = x * x;
    #pragma unroll
    for (int m = 1; m < 16; ++m) {
        float y = base[8 * m];
        float s = y * y;
        c = c + s;
    }
    return c;
}

__device__ __forceinline__ float np_combine16(const float* c) {
    #pragma clang fp contract(off)
    float L = ((c[0] + c[1]) + (c[2] + c[3])) + ((c[4] + c[5]) + (c[6] + c[7]));
    float R = ((c[8] + c[9]) + (c[10] + c[11])) + ((c[12] + c[13]) + (c[14] + c[15]));
    return L + R;
}

// ---- top-3 insertion (strict <, preserves first-insertion on ties) ----
__device__ __forceinline__ void ins3(float m, int k,
                                     float& v0, float& v1, float& v2,
                                     int& i0, int& i1, int& i2) {
    if (m < v0)      { v2 = v1; i2 = i1; v1 = v0; i1 = i0; v0 = m; i0 = k; }
    else if (m < v1) { v2 = v1; i2 = i1; v1 = m;  i1 = k; }
    else if (m < v2) { v2 = m;  i2 = k; }
}

// ---- top-3 insertion with index tiebreak (deterministic, order-independent) ----
__device__ __forceinline__ void ins3tb(float m, int k,
                                       float& v0, float& v1, float& v2,
                                       int& i0, int& i1, int& i2) {
    if (m < v0 || (m == v0 && k < i0))      { v2 = v1; i2 = i1; v1 = v0; i1 = i0; v0 = m; i0 = k; }
    else if (m < v1 || (m == v1 && k < i1)) { v2 = v1; i2 = i1; v1 = m;  i1 = k; }
    else if (m < v2 || (m == v2 && k < i2)) { v2 = m;  i2 = k; }
}

// ---- top-6 insertion with index tiebreak ----
__device__ __forceinline__ void ins6tb(float v, int id, float* bv, int* bi) {
    #pragma unroll
    for (int x = 0; x < 6; ++x) {
        if (v < bv[x] || (v == bv[x] && id < bi[x])) {
            #pragma unroll
            for (int d = 5; d > x; --d) { bv[d] = bv[d - 1]; bi[d] = bi[d - 1]; }
            bv[x] = v; bi[x] = id;
            break;
        }
    }
}

// ---------------- kernel 1: zero counts ----------------
__global__ void zero_counts_kernel(int* __restrict__ counts, int K) {
    int i = blockIdx.x * 256 + threadIdx.x;
    if (i < K) counts[i] = 0;
}

// ---------------- kernel 2: numpy-faithful code norms ||e_k||^2 ----------------
__global__ void code_norms_np_kernel(const float* __restrict__ e, float* __restrict__ e2) {
    __shared__ float buf[DDIM];
    __shared__ float ch[16];
    int k = blockIdx.x;
    int t = threadIdx.x;  // 64 threads = 1 wave
    float4 v = *(const float4*)&e[(size_t)k * DDIM + t * 4];
    *(float4*)&buf[t * 4] = v;
    __syncthreads();
    if (t < 16) ch[t] = np_sq_chain(buf, t);
    __syncthreads();
    if (t == 0) e2[k] = np_combine16(ch);
}

// ---------------- kernel 2b: convert e -> bf16 panel layout ----------------
// ebf_p[tile=k/32][d8=0..31][r=k%32][8 shorts]; tile = 16KB contiguous.
__global__ void convert_permute_e_kernel(const float* __restrict__ e, char* __restrict__ ebf_p) {
    int id = blockIdx.x * 256 + threadIdx.x;   // id = k*32 + d8, total K*32
    int k = id >> 5, d8 = id & 31;
    const float* s = &e[(size_t)k * DDIM + d8 * 8];
    float4 f0 = *(const float4*)s;
    float4 f1 = *(const float4*)(s + 4);
    short8v v;
    v[0] = f2bf(f0.x); v[1] = f2bf(f0.y); v[2] = f2bf(f0.z); v[3] = f2bf(f0.w);
    v[4] = f2bf(f1.x); v[5] = f2bf(f1.y); v[6] = f2bf(f1.z); v[7] = f2bf(f1.w);
    *(short8v*)(ebf_p + ((size_t)(k >> 5) << 14) + d8 * 512 + (k & 31) * 16) = v;
}

// ---------------- kernel 3: inverted-dataflow MFMA candidate kernel ----------------
// DATAFLOW INVERSION (round-4 discriminator): rounds 0-3 all kept a persistent
// per-wave z-fragment (32-64 VGPRs) that either spilled to scratch (WRITE_SIZE
// 35-110MB, VGPR_Count 32-64 < needed) or starved the scheduler of temps, and
// re-read z from HBM once per split. All four landed 277-350us, pipes ~90% idle.
// This version has NO persistent operand registers and NO loop synchronization:
//   - block = 32 z-rows staged ONCE into a 16KB LDS panel (z read once total);
//   - 8 waves each own 8 of the 64 code tiles, streamed straight from global
//     (L2-resident 1MB codebook; ~1GB aggregate L2 reads ~= 30us floor);
//   - per-kk registers are all short-lived: a0,a1 + zb0,zb1 + 4 accs ~= 56 VGPR
//     -> no spill (falsifiable: WRITE_SIZE must collapse to ~logical), 8 w/EU.
// Output: per-row GLOBAL top-6 candidates over all 2048 codes (value-then-index
// deterministic merge), bit-identical scores to previous rounds.
__global__ __attribute__((amdgpu_flat_work_group_size(512, 512)))
void vq_cand_kernel(const float* __restrict__ z, const char* __restrict__ ebf_p,
                    const float* __restrict__ e2, float* __restrict__ cand_v,
                    u16* __restrict__ cand_i, int N) {
    __shared__ __align__(16) char zp[TILE_BYTES];   // 32 rows x 256 d bf16, panel layout
    __shared__ float e2s[2048];
    __shared__ float mbuf_v[8][32][3];
    __shared__ int   mbuf_i[8][32][3];
    const int t    = threadIdx.x;
    const int w    = t >> 6;        // wave 0..7
    const int lane = t & 63;
    const int quad = lane >> 4;
    const int l15  = lane & 15;
    const int rw0  = blockIdx.x * ROWS_PER_BLOCK;

    // ---- stage z panel: zp[c=dim/8][r=row][16B], c in 0..31, r in 0..31 ----
    // unit u: r = u&31 (fastest), c = u>>5 -> wave covers rows 0..31 x 2 dims
    // chunks = full 64B lines on global (coalesced), contiguous 512B ds_writes.
    #pragma unroll
    for (int half = 0; half < 2; ++half) {
        int u = t + half * 512;
        int r = u & 31, c = u >> 5;
        const float* src = &z[(size_t)(rw0 + r) * DDIM + c * 8];
        float4 f0 = *(const float4*)src;
        float4 f1 = *(const float4*)(src + 4);
        short8v v;
        v[0] = f2bf(f0.x); v[1] = f2bf(f0.y); v[2] = f2bf(f0.z); v[3] = f2bf(f0.w);
        v[4] = f2bf(f1.x); v[5] = f2bf(f1.y); v[6] = f2bf(f1.z); v[7] = f2bf(f1.w);
        *(short8v*)(zp + c * 512 + r * 16) = v;
    }
    // e2 -> LDS (one float4 per thread)
    *(float4*)&e2s[t * 4] = *(const float4*)&e2[t * 4];
    __syncthreads();   // only barrier before the merge phase

    // per-lane top-3 state: panel0 = rows rw0+l15, panel1 = rows rw0+16+l15
    float va0 = 3.4e38f, va1 = 3.4e38f, va2 = 3.4e38f;
    int   ia0 = 0x7fff,  ia1 = 0x7fff,  ia2 = 0x7fff;
    float vb0 = 3.4e38f, vb1 = 3.4e38f, vb2 = 3.4e38f;
    int   ib0 = 0x7fff,  ib1 = 0x7fff,  ib2 = 0x7fff;

    // ---- 8 tiles per wave (ascending k), streamed from global/L2 ----
    #pragma unroll 1
    for (int i = 0; i < 8; ++i) {
        const int tt = w + i * 8;
        const char* tg = ebf_p + (size_t)tt * TILE_BYTES + quad * 512 + l15 * 16;
        const char* zq = zp + quad * 512 + l15 * 16;

        float4v acc00 = (float4v)0.0f, acc01 = (float4v)0.0f;
        float4v acc10 = (float4v)0.0f, acc11 = (float4v)0.0f;

        #pragma unroll
        for (int kk = 0; kk < 8; ++kk) {
            short8v a0  = *(const short8v*)(tg + kk * 2048);          // codes 0..15
            short8v a1  = *(const short8v*)(tg + kk * 2048 + 256);    // codes 16..31
            short8v zb0 = *(const short8v*)(zq + kk * 2048);          // rows 0..15
            short8v zb1 = *(const short8v*)(zq + kk * 2048 + 256);    // rows 16..31
            acc00 = __builtin_amdgcn_mfma_f32_16x16x32_bf16(a0, zb0, acc00, 0, 0, 0);
            acc01 = __builtin_amdgcn_mfma_f32_16x16x32_bf16(a1, zb0, acc01, 0, 0, 0);
            acc10 = __builtin_amdgcn_mfma_f32_16x16x32_bf16(a0, zb1, acc10, 0, 0, 0);
            acc11 = __builtin_amdgcn_mfma_f32_16x16x32_bf16(a1, zb1, acc11, 0, 0, 0);
        }

        // epilogue: fold m(k)=e2[k]-2S into per-row top-3 (same visit
        // interleave as rounds 0-3 -> bit-identical scores & tie behavior)
        const int kb = tt * TILE_CODES;
        float4 e2a = *(const float4*)&e2s[kb + quad * 4];
        float4 e2b = *(const float4*)&e2s[kb + 16 + quad * 4];
        float m;
        m = fmaf(-2.0f, acc00[0], e2a.x); ins3(m, kb + quad * 4 + 0,      va0, va1, va2, ia0, ia1, ia2);
        m = fmaf(-2.0f, acc01[0], e2b.x); ins3(m, kb + 16 + quad * 4 + 0, va0, va1, va2, ia0, ia1, ia2);
        m = fmaf(-2.0f, acc00[1], e2a.y); ins3(m, kb + quad * 4 + 1,      va0, va1, va2, ia0, ia1, ia2);
        m = fmaf(-2.0f, acc01[1], e2b.y); ins3(m, kb + 16 + quad * 4 + 1, va0, va1, va2, ia0, ia1, ia2);
        m = fmaf(-2.0f, acc00[2], e2a.z); ins3(m, kb + quad * 4 + 2,      va0, va1, va2, ia0, ia1, ia2);
        m = fmaf(-2.0f, acc01[2], e2b.z); ins3(m, kb + 16 + quad * 4 + 2, va0, va1, va2, ia0, ia1, ia2);
        m = fmaf(-2.0f, acc00[3], e2a.w); ins3(m, kb + quad * 4 + 3,      va0, va1, va2, ia0, ia1, ia2);
        m = fmaf(-2.0f, acc01[3], e2b.w); ins3(m, kb + 16 + quad * 4 + 3, va0, va1, va2, ia0, ia1, ia2);

        m = fmaf(-2.0f, acc10[0], e2a.x); ins3(m, kb + quad * 4 + 0,      vb0, vb1, vb2, ib0, ib1, ib2);
        m = fmaf(-2.0f, acc11[0], e2b.x); ins3(m, kb + 16 + quad * 4 + 0, vb0, vb1, vb2, ib0, ib1, ib2);
        m = fmaf(-2.0f, acc10[1], e2a.y); ins3(m, kb + quad * 4 + 1,      vb0, vb1, vb2, ib0, ib1, ib2);
        m = fmaf(-2.0f, acc11[1], e2b.y); ins3(m, kb + 16 + quad * 4 + 1, vb0, vb1, vb2, ib0, ib1, ib2);
        m = fmaf(-2.0f, acc10[2], e2a.z); ins3(m, kb + quad * 4 + 2,      vb0, vb1, vb2, ib0, ib1, ib2);
        m = fmaf(-2.0f, acc11[2], e2b.z); ins3(m, kb + 16 + quad * 4 + 2, vb0, vb1, vb2, ib0, ib1, ib2);
        m = fmaf(-2.0f, acc10[3], e2a.w); ins3(m, kb + quad * 4 + 3,      vb0, vb1, vb2, ib0, ib1, ib2);
        m = fmaf(-2.0f, acc11[3], e2b.w); ins3(m, kb + 16 + quad * 4 + 3, vb0, vb1, vb2, ib0, ib1, ib2);
    }

    // ---- cross-quad merge (both panels): 4 quads x top-3 -> wave top-3/row ----
    {
        float am0 = 3.4e38f, am1 = 3.4e38f, am2 = 3.4e38f;
        int   ak0 = 0x7fffffff, ak1 = 0x7fffffff, ak2 = 0x7fffffff;
        float bm0 = 3.4e38f, bm1 = 3.4e38f, bm2 = 3.4e38f;
        int   bk0 = 0x7fffffff, bk1 = 0x7fffffff, bk2 = 0x7fffffff;
        #pragma unroll
        for (int q = 0; q < 4; ++q) {
            int src = l15 + q * 16;
            float m0 = __shfl(va0, src); int k0 = __shfl(ia0, src);
            float m1 = __shfl(va1, src); int k1 = __shfl(ia1, src);
            float m2 = __shfl(va2, src); int k2 = __shfl(ia2, src);
            ins3tb(m0, k0, am0, am1, am2, ak0, ak1, ak2);
            ins3tb(m1, k1, am0, am1, am2, ak0, ak1, ak2);
            ins3tb(m2, k2, am0, am1, am2, ak0, ak1, ak2);
            m0 = __shfl(vb0, src); k0 = __shfl(ib0, src);
            m1 = __shfl(vb1, src); k1 = __shfl(ib1, src);
            m2 = __shfl(vb2, src); k2 = __shfl(ib2, src);
            ins3tb(m0, k0, bm0, bm1, bm2, bk0, bk1, bk2);
            ins3tb(m1, k1, bm0, bm1, bm2, bk0, bk1, bk2);
            ins3tb(m2, k2, bm0, bm1, bm2, bk0, bk1, bk2);
        }
        if (quad == 0) {
            mbuf_v[w][l15][0] = am0; mbuf_i[w][l15][0] = ak0;
            mbuf_v[w][l15][1] = am1; mbuf_i[w][l15][1] = ak1;
            mbuf_v[w][l15][2] = am2; mbuf_i[w][l15][2] = ak2;
        } else if (quad == 1) {
            mbuf_v[w][16 + l15][0] = bm0; mbuf_i[w][16 + l15][0] = bk0;
            mbuf_v[w][16 + l15][1] = bm1; mbuf_i[w][16 + l15][1] = bk1;
            mbuf_v[w][16 + l15][2] = bm2; mbuf_i[w][16 + l15][2] = bk2;
        }
    }
    __syncthreads();

    // ---- cross-wave merge: 8 waves x 3 -> global top-6 per row ----
    if (t < 32) {
        float fv[6]; int fi[6];
        #pragma unroll
        for (int x = 0; x < 6; ++x) { fv[x] = 3.4e38f; fi[x] = 0x7fffffff; }
        #pragma unroll
        for (int wv = 0; wv < 8; ++wv) {
            #pragma unroll
            for (int j = 0; j < 3; ++j)
                ins6tb(mbuf_v[wv][t][j], mbuf_i[wv][t][j], fv, fi);
        }
        size_t base = (size_t)(rw0 + t) * 6;
        #pragma unroll
        for (int j = 0; j < 6; ++j) {
            cand_v[base + j] = fv[j];
            cand_i[base + j] = (u16)fi[j];
        }
    }
}

// ---------------- kernel 4: prefilter + np-faithful re-rank + gather + loss ----------------
// One wave per row. 6 global-top candidates -> exact fp64 dots, numpy-fp32-
// faithful distance ranking, fused gather + partials.
__global__ void refine_fused_kernel(const float* __restrict__ z, const float* __restrict__ e,
                                    const float* __restrict__ e2np,
                                    const float* __restrict__ cand_v,
                                    const u16* __restrict__ cand_i,
                                    int* __restrict__ counts, float* __restrict__ partials,
                                    float* __restrict__ out_zq, float* __restrict__ out_idx,
                                    int N) {
    __shared__ float buf[4][DDIM];
    __shared__ float ch[4][16];
    __shared__ float wsum[4];
    const int w = threadIdx.x >> 6;
    const int t = threadIdx.x & 63;
    const int n = blockIdx.x * 4 + w;

    float4 zv = *(const float4*)&z[(size_t)n * DDIM + t * 4];
    *(float4*)&buf[w][t * 4] = zv;
    __syncthreads();
    if (t < 16) ch[w][t] = np_sq_chain(buf[w], t);
    __syncthreads();

    // ---- candidates are already the global top-6 (value,idx)-sorted ----
    float bv[6]; int bi[6];
    #pragma unroll
    for (int c = 0; c < 6; ++c) {
        bv[c] = cand_v[(size_t)n * 6 + c];
        bi[c] = (int)cand_i[(size_t)n * 6 + c];
    }

    float dotf[6];
    #pragma unroll
    for (int c = 0; c < 6; ++c) {
        int k = bi[c];
        float4 ev = *(const float4*)&e[(size_t)k * DDIM + t * 4];
        double p = (double)zv.x * (double)ev.x + (double)zv.y * (double)ev.y
                 + (double)zv.z * (double)ev.z + (double)zv.w * (double)ev.w;
        #pragma unroll
        for (int o = 32; o > 0; o >>= 1) p += __shfl_down(p, o);
        dotf[c] = (float)p;   // correctly-rounded fp32 of exact dot
    }

    int bk = 0;
    if (t == 0) {
        #pragma clang fp contract(off)
        float sx = np_combine16(ch[w]);
        float bd = 3.4e38f;
        bk = 0x7fffffff;
        #pragma unroll
        for (int c = 0; c < 6; ++c) {
            float twod = 2.0f * dotf[c];
            float t1 = sx - twod;
            float d2v = t1 + e2np[bi[c]];
            d2v = fmaxf(d2v, 0.0f);
            float d = sqrtf(d2v);
            if (d < bd || (d == bd && bi[c] < bk)) { bd = d; bk = bi[c]; }
        }
    }
    int wk = __shfl(bk, 0);

    float4 ev = *(const float4*)&e[(size_t)wk * DDIM + t * 4];
    *(float4*)&out_zq[(size_t)n * DDIM + t * 4] = ev;
    float dx = zv.x - ev.x, dy = zv.y - ev.y, dz = zv.z - ev.z, dw = zv.w - ev.w;
    float sq = dx * dx + dy * dy + dz * dz + dw * dw;
    #pragma unroll
    for (int o = 32; o > 0; o >>= 1) sq += __shfl_down(sq, o);
    if (t == 0) {
        wsum[w] = sq;
        atomicAdd(&counts[wk], 1);
        out_idx[n] = (float)wk;
    }
    __syncthreads();
    if (threadIdx.x == 0)
        partials[blockIdx.x] = wsum[0] + wsum[1] + wsum[2] + wsum[3];
}

// ---------------- kernel 5: finalize loss ----------------
__global__ void finalize_kernel(const int* __restrict__ counts, const float* __restrict__ partials,
                                float* __restrict__ out_loss, int K, int NB,
                                float invN, float invND) {
    int t = threadIdx.x;
    double ent = 0.0, sq = 0.0;
    for (int k = t; k < K; k += 256) {
        float p = (float)counts[k] * invN;
        ent += (double)(p * logf(p + 1e-10f));
    }
    for (int i = t; i < NB; i += 256) sq += (double)partials[i];
    #pragma unroll
    for (int o = 32; o > 0; o >>= 1) {
        ent += __shfl_down(ent, o);
        sq  += __shfl_down(sq, o);
    }
    __shared__ double e4[4], s4[4];
    if ((t & 63) == 0) { e4[t >> 6] = ent; s4[t >> 6] = sq; }
    __syncthreads();
    if (t == 0) {
        double esum = e4[0] + e4[1] + e4[2] + e4[3];
        double ssum = s4[0] + s4[1] + s4[2] + s4[3];
        float perp = expf((float)(-esum));
        float mean = (float)ssum * invND;
        out_loss[0] = 1.25f * mean - 0.01f * perp;
    }
}

extern "C" void kernel_launch(void* const* d_in, const int* in_sizes, int n_in,
                              void* d_out, int out_size, void* d_ws, size_t ws_size,
                              hipStream_t stream) {
    const float* z = (const float*)d_in[0];
    const float* e = (const float*)d_in[1];
    const int N = in_sizes[0] / DDIM;   // 32768
    const int K = in_sizes[1] / DDIM;   // 2048

    float* out      = (float*)d_out;
    float* out_zq   = out;
    float* out_loss = out + (size_t)N * DDIM;
    float* out_idx  = out_loss + 1;

    // ws layout (bytes):
    //   counts[K]            @ 0        (8 KB)
    //   e2np[K]              @ 8192     (8 KB)
    //   partials[N/4]        @ 16384    (32 KB)
    //   cand_v[N][6] f32     @ 49152    (768 KB)
    //   cand_i[N][6] u16     @ 835584   (384 KB)
    //   ebf_p (1 MB panels)  @ 1228800  -> total ~2.2 MB
    int*   counts   = (int*)d_ws;
    float* e2np     = (float*)((char*)d_ws + 8192);
    float* partials = (float*)((char*)d_ws + 16384);
    float* cand_v   = (float*)((char*)d_ws + 49152);
    u16*   cand_i   = (u16*)((char*)d_ws + 835584);
    char*  ebf_p    = (char*)d_ws + 1228800;

    zero_counts_kernel<<<(K + 255) / 256, 256, 0, stream>>>(counts, K);
    code_norms_np_kernel<<<K, 64, 0, stream>>>(e, e2np);
    convert_permute_e_kernel<<<K * 32 / 256, 256, 0, stream>>>(e, ebf_p);
    vq_cand_kernel<<<N / ROWS_PER_BLOCK, 512, 0, stream>>>(z, ebf_p, e2np,
                                                           cand_v, cand_i, N);
    refine_fused_kernel<<<N / 4, 256, 0, stream>>>(z, e, e2np, cand_v, cand_i,
                                                   counts, partials, out_zq, out_idx, N);
    finalize_kernel<<<1, 256, 0, stream>>>(counts, partials, out_loss, K, N / 4,
                                           1.0f / (float)N, 1.0f / (float)(N * DDIM));
}

// Round 5
// 441.620 us; speedup vs baseline: 1.2082x; 1.2082x over previous
//
#include <hip/hip_runtime.h>
#include <math.h>

#define DDIM 256
#define NSPLIT 4
#define TILES_PER_SPLIT 16   // 16 tiles x 32 codes = 512 codes per split
#define TILE_CODES 32
#define TILE_BYTES 16384     // 32 codes x 256 dims x 2B (panel layout)
#define ROWS_PER_BLOCK 128   // 4 waves x 32 rows

typedef __attribute__((ext_vector_type(8))) short short8v;
typedef __attribute__((ext_vector_type(4))) float float4v;
typedef unsigned int u32;
typedef unsigned short u16;

// ---- RNE float -> bf16 ----
__device__ __forceinline__ short f2bf(float x) {
    u32 u = __float_as_uint(x);
    u = u + 0x7fffu + ((u >> 16) & 1u);
    return (short)(u >> 16);
}

// ---- async global->LDS, 16B per lane; lds dst = wave-uniform base + lane*16 ----
__device__ __forceinline__ void gload_lds16(const void* g, void* l) {
    __builtin_amdgcn_global_load_lds(
        (const __attribute__((address_space(1))) u32*)g,
        (__attribute__((address_space(3))) u32*)l, 16, 0, 0);
}

// ---- numpy pairwise-sum simulation (bit-faithful for n=256 contiguous) ----
__device__ __forceinline__ float np_sq_chain(const float* v, int lane) {
    #pragma clang fp contract(off)
    const int half = lane >> 3, j = lane & 7;
    const float* base = v + half * 128 + j;
    float x = base[0];
    float c = x * x;
    #pragma unroll
    for (int m = 1; m < 16; ++m) {
        float y = base[8 * m];
        float s = y * y;
        c = c + s;
    }
    return c;
}

__device__ __forceinline__ float np_combine16(const float* c) {
    #pragma clang fp contract(off)
    float L = ((c[0] + c[1]) + (c[2] + c[3])) + ((c[4] + c[5]) + (c[6] + c[7]));
    float R = ((c[8] + c[9]) + (c[10] + c[11])) + ((c[12] + c[13]) + (c[14] + c[15]));
    return L + R;
}

// ---- top-3 insertion (strict <, preserves first-insertion on ties) ----
__device__ __forceinline__ void ins3(float m, int k,
                                     float& v0, float& v1, float& v2,
                                     int& i0, int& i1, int& i2) {
    if (m < v0)      { v2 = v1; i2 = i1; v1 = v0; i1 = i0; v0 = m; i0 = k; }
    else if (m < v1) { v2 = v1; i2 = i1; v1 = m;  i1 = k; }
    else if (m < v2) { v2 = m;  i2 = k; }
}

// ---------------- kernel 1: zero counts ----------------
__global__ void zero_counts_kernel(int* __restrict__ counts, int K) {
    int i = blockIdx.x * 256 + threadIdx.x;
    if (i < K) counts[i] = 0;
}

// ---------------- kernel 2: numpy-faithful code norms ||e_k||^2 ----------------
__global__ void code_norms_np_kernel(const float* __restrict__ e, float* __restrict__ e2) {
    __shared__ float buf[DDIM];
    __shared__ float ch[16];
    int k = blockIdx.x;
    int t = threadIdx.x;  // 64 threads = 1 wave
    float4 v = *(const float4*)&e[(size_t)k * DDIM + t * 4];
    *(float4*)&buf[t * 4] = v;
    __syncthreads();
    if (t < 16) ch[t] = np_sq_chain(buf, t);
    __syncthreads();
    if (t == 0) e2[k] = np_combine16(ch);
}

// ---------------- kernel 2b: convert e -> bf16 panel layout ----------------
// ebf_p[tile=k/32][d8=0..31][r=k%32][8 shorts]; tile = 16KB contiguous.
__global__ void convert_permute_e_kernel(const float* __restrict__ e, char* __restrict__ ebf_p) {
    int id = blockIdx.x * 256 + threadIdx.x;   // id = k*32 + d8, total K*32
    int k = id >> 5, d8 = id & 31;
    const float* s = &e[(size_t)k * DDIM + d8 * 8];
    float4 f0 = *(const float4*)s;
    float4 f1 = *(const float4*)(s + 4);
    short8v v;
    v[0] = f2bf(f0.x); v[1] = f2bf(f0.y); v[2] = f2bf(f0.z); v[3] = f2bf(f0.w);
    v[4] = f2bf(f1.x); v[5] = f2bf(f1.y); v[6] = f2bf(f1.z); v[7] = f2bf(f1.w);
    *(short8v*)(ebf_p + ((size_t)(k >> 5) << 14) + d8 * 512 + (k & 31) * 16) = v;
}

// ---------------- kernel 3: bf16 MFMA candidate kernel ----------------
// REGISTER-BUDGET DISCRIMINATOR (round 5). Unified theory of rounds 0-4:
// gfx950 has a UNIFIED VGPR/AGPR file; the MFMA accumulators count against
// the same budget as VGPRs. Every prior round's waves_per_eu attribute (or
// the backend's default occupancy heuristic) implied a 64-128 reg budget,
// while true peak demand (zf fragments + AGPR accs + staging temps) was
// ~130-150 -> the allocator spilled the overflow to scratch. Scratch is
// HBM-backed and the spill->reload pairs sit serially in the per-tile
// dependency chain (~900cy each) -> the ~5kcy/tile stall that made every
// pipe idle regardless of sync structure, occupancy, or dataflow.
// Signature: WRITE_SIZE 35-110MB (vs <4MB logical) in ALL rounds.
// Fix: waves_per_eu(2,4) -> 256-reg budget. Everything else is byte-identical
// to round 1 (best measured structure, 277us, verified semantics).
// Falsifiable: VGPR_Count must rise to >=90 and WRITE_SIZE collapse to <10MB.
__global__ __attribute__((amdgpu_flat_work_group_size(256, 256)))
__attribute__((amdgpu_waves_per_eu(2, 4)))
void vq_cand_kernel(const float* __restrict__ z, const char* __restrict__ ebf_p,
                    const float* __restrict__ e2, float* __restrict__ cand_v,
                    u16* __restrict__ cand_i, int N) {
    __shared__ __align__(16) char smem[2][TILE_BYTES];
    __shared__ float e2s[512];
    const int t    = threadIdx.x;
    const int w    = t >> 6;
    const int lane = t & 63;
    const int quad = lane >> 4;
    const int l15  = lane & 15;
    const int s    = blockIdx.y;
    const int row0 = blockIdx.x * ROWS_PER_BLOCK;
    const int rw0  = row0 + w * 32;

    const char* tile_base = ebf_p + (size_t)s * TILES_PER_SPLIT * TILE_BYTES;

    // 2-deep prefetch: T0 -> buf0, T1 -> buf1 (issued first so their latency
    // overlaps the z-fragment load+convert phase)
    {
        const char* src0 = tile_base + w * 4096 + lane * 16;
        char* dst0 = smem[0] + w * 4096;
        char* dst1 = smem[1] + w * 4096;
        #pragma unroll
        for (int q = 0; q < 4; ++q) gload_lds16(src0 + q * 1024, dst0 + q * 1024);
        #pragma unroll
        for (int q = 0; q < 4; ++q) gload_lds16(src0 + TILE_BYTES + q * 1024, dst1 + q * 1024);
    }

    // e2 for this split -> LDS once
    e2s[t]       = e2[s * 512 + t];
    e2s[t + 256] = e2[s * 512 + t + 256];

    // ---- persistent z fragments: 32 rows x 256 dims per wave (64 VGPRs) ----
    short8v zf0[8], zf1[8];
    {
        const float* zrA = &z[(size_t)(rw0 + l15) * DDIM];
        #pragma unroll
        for (int kk = 0; kk < 8; ++kk) {
            int d0 = kk * 32 + quad * 8;
            float4 f0 = *(const float4*)&zrA[d0];
            float4 f1 = *(const float4*)&zrA[d0 + 4];
            short8v v;
            v[0] = f2bf(f0.x); v[1] = f2bf(f0.y); v[2] = f2bf(f0.z); v[3] = f2bf(f0.w);
            v[4] = f2bf(f1.x); v[5] = f2bf(f1.y); v[6] = f2bf(f1.z); v[7] = f2bf(f1.w);
            zf0[kk] = v;
        }
        const float* zrB = &z[(size_t)(rw0 + 16 + l15) * DDIM];
        #pragma unroll
        for (int kk = 0; kk < 8; ++kk) {
            int d0 = kk * 32 + quad * 8;
            float4 f0 = *(const float4*)&zrB[d0];
            float4 f1 = *(const float4*)&zrB[d0 + 4];
            short8v v;
            v[0] = f2bf(f0.x); v[1] = f2bf(f0.y); v[2] = f2bf(f0.z); v[3] = f2bf(f0.w);
            v[4] = f2bf(f1.x); v[5] = f2bf(f1.y); v[6] = f2bf(f1.z); v[7] = f2bf(f1.w);
            zf1[kk] = v;
        }
    }

    float va0 = 3.4e38f, va1 = 3.4e38f, va2 = 3.4e38f;
    int   ia0 = 0x7fff,  ia1 = 0x7fff,  ia2 = 0x7fff;
    float vb0 = 3.4e38f, vb1 = 3.4e38f, vb2 = 3.4e38f;
    int   ib0 = 0x7fff,  ib1 = 0x7fff,  ib2 = 0x7fff;

    // all waves' e2s ds_writes complete before the first barrier
    asm volatile("s_waitcnt lgkmcnt(0)" ::: "memory");

    #pragma unroll 1
    for (int tt = 0; tt < TILES_PER_SPLIT; ++tt) {
        // wait OWN tile-tt loads only; keep T(tt+1)'s 4 loads in flight
        if (tt < TILES_PER_SPLIT - 1)
            asm volatile("s_waitcnt vmcnt(4)" ::: "memory");
        else
            asm volatile("s_waitcnt vmcnt(0)" ::: "memory");
        __builtin_amdgcn_s_barrier();   // everyone's tile-tt data is in LDS

        const char* es = smem[tt & 1];
        float4v acc00 = (float4v)0.0f, acc01 = (float4v)0.0f;
        float4v acc10 = (float4v)0.0f, acc11 = (float4v)0.0f;

        #pragma unroll
        for (int kk = 0; kk < 8; ++kk) {
            int c = kk * 4 + quad;  // d8 chunk
            short8v a0 = *(const short8v*)(es + c * 512 + l15 * 16);        // codes 0..15
            short8v a1 = *(const short8v*)(es + c * 512 + (16 + l15) * 16); // codes 16..31
            acc00 = __builtin_amdgcn_mfma_f32_16x16x32_bf16(a0, zf0[kk], acc00, 0, 0, 0);
            acc01 = __builtin_amdgcn_mfma_f32_16x16x32_bf16(a1, zf0[kk], acc01, 0, 0, 0);
            acc10 = __builtin_amdgcn_mfma_f32_16x16x32_bf16(a0, zf1[kk], acc10, 0, 0, 0);
            acc11 = __builtin_amdgcn_mfma_f32_16x16x32_bf16(a1, zf1[kk], acc11, 0, 0, 0);
        }

        // epilogue: fold tile scores m(k)=e2[k]-2S into per-row top-3
        // (same per-row code visit order as before -> bit-identical candidates)
        const int kloc  = tt * TILE_CODES;
        const int kbase = s * 512 + kloc;
        #pragma unroll
        for (int reg = 0; reg < 4; ++reg) {
            int cl0 = quad * 4 + reg;
            int cl1 = 16 + quad * 4 + reg;
            float e20 = e2s[kloc + cl0];
            float e21 = e2s[kloc + cl1];
            float m00 = fmaf(-2.0f, acc00[reg], e20);
            ins3(m00, kbase + cl0, va0, va1, va2, ia0, ia1, ia2);
            float m01 = fmaf(-2.0f, acc01[reg], e21);
            ins3(m01, kbase + cl1, va0, va1, va2, ia0, ia1, ia2);
            float m10 = fmaf(-2.0f, acc10[reg], e20);
            ins3(m10, kbase + cl0, vb0, vb1, vb2, ib0, ib1, ib2);
            float m11 = fmaf(-2.0f, acc11[reg], e21);
            ins3(m11, kbase + cl1, vb0, vb1, vb2, ib0, ib1, ib2);
        }

        // all waves done READING buf[tt&1] before anyone refills it
        asm volatile("s_waitcnt lgkmcnt(0)" ::: "memory");
        __builtin_amdgcn_s_barrier();

        if (tt + 2 < TILES_PER_SPLIT) {
            const char* src = tile_base + (size_t)(tt + 2) * TILE_BYTES + w * 4096 + lane * 16;
            char* dst = smem[tt & 1] + w * 4096;
            #pragma unroll
            for (int q = 0; q < 4; ++q) gload_lds16(src + q * 1024, dst + q * 1024);
        }
    }

    // ---- cross-quad merge via shuffles: 4 quads x top-3 -> split top-3 ----
    {
        float am0 = 3.4e38f, am1 = 3.4e38f, am2 = 3.4e38f;
        int   ak0 = 0x7fff,  ak1 = 0x7fff,  ak2 = 0x7fff;
        float bm0 = 3.4e38f, bm1 = 3.4e38f, bm2 = 3.4e38f;
        int   bk0 = 0x7fff,  bk1 = 0x7fff,  bk2 = 0x7fff;
        #pragma unroll
        for (int q = 0; q < 4; ++q) {
            int src = l15 + q * 16;
            float m0 = __shfl(va0, src); int k0 = __shfl(ia0, src);
            float m1 = __shfl(va1, src); int k1 = __shfl(ia1, src);
            float m2 = __shfl(va2, src); int k2 = __shfl(ia2, src);
            ins3(m0, k0, am0, am1, am2, ak0, ak1, ak2);
            ins3(m1, k1, am0, am1, am2, ak0, ak1, ak2);
            ins3(m2, k2, am0, am1, am2, ak0, ak1, ak2);
            m0 = __shfl(vb0, src); k0 = __shfl(ib0, src);
            m1 = __shfl(vb1, src); k1 = __shfl(ib1, src);
            m2 = __shfl(vb2, src); k2 = __shfl(ib2, src);
            ins3(m0, k0, bm0, bm1, bm2, bk0, bk1, bk2);
            ins3(m1, k1, bm0, bm1, bm2, bk0, bk1, bk2);
            ins3(m2, k2, bm0, bm1, bm2, bk0, bk1, bk2);
        }
        // split-major layout cand[s][n][3]: block writes contiguous regions
        if (quad == 0) {
            size_t base = ((size_t)s * N + (rw0 + l15)) * 3;
            cand_v[base]     = am0;  cand_i[base]     = (u16)ak0;
            cand_v[base + 1] = am1;  cand_i[base + 1] = (u16)ak1;
            cand_v[base + 2] = am2;  cand_i[base + 2] = (u16)ak2;
        } else if (quad == 1) {
            size_t base = ((size_t)s * N + (rw0 + 16 + l15)) * 3;
            cand_v[base]     = bm0;  cand_i[base]     = (u16)bk0;
            cand_v[base + 1] = bm1;  cand_i[base + 1] = (u16)bk1;
            cand_v[base + 2] = bm2;  cand_i[base + 2] = (u16)bk2;
        }
    }
}

// ---------------- kernel 4: prefilter + np-faithful re-rank + gather + loss ----------------
// One wave per row. Prefilter 12 bf16-scored candidates -> top-6, exact fp64
// dots on 6, numpy-fp32-faithful distance ranking, fused gather + partials.
__global__ void refine_fused_kernel(const float* __restrict__ z, const float* __restrict__ e,
                                    const float* __restrict__ e2np,
                                    const float* __restrict__ cand_v,
                                    const u16* __restrict__ cand_i,
                                    int* __restrict__ counts, float* __restrict__ partials,
                                    float* __restrict__ out_zq, float* __restrict__ out_idx,
                                    int N) {
    __shared__ float buf[4][DDIM];
    __shared__ float ch[4][16];
    __shared__ float wsum[4];
    const int w = threadIdx.x >> 6;
    const int t = threadIdx.x & 63;
    const int n = blockIdx.x * 4 + w;

    float4 zv = *(const float4*)&z[(size_t)n * DDIM + t * 4];
    *(float4*)&buf[w][t * 4] = zv;
    __syncthreads();
    if (t < 16) ch[w][t] = np_sq_chain(buf[w], t);
    __syncthreads();

    // ---- prefilter: 12 -> top-6 by bf16 score (uniform across wave) ----
    // read order sp=0..3, j=0..2 matches the original n*12+c order exactly
    float bv[6]; int bi[6];
    #pragma unroll
    for (int c = 0; c < 6; ++c) { bv[c] = 3.4e38f; bi[c] = 0x7fffffff; }
    #pragma unroll
    for (int c = 0; c < 12; ++c) {
        int sp = c / 3, j = c - sp * 3;
        size_t off = ((size_t)sp * N + n) * 3 + j;
        float v  = cand_v[off];
        int   id = (int)cand_i[off];
        #pragma unroll
        for (int x = 0; x < 6; ++x) {
            if (v < bv[x] || (v == bv[x] && id < bi[x])) {
                for (int d = 5; d > x; --d) { bv[d] = bv[d - 1]; bi[d] = bi[d - 1]; }
                bv[x] = v; bi[x] = id;
                break;
            }
        }
    }

    float dotf[6];
    #pragma unroll
    for (int c = 0; c < 6; ++c) {
        int k = bi[c];
        float4 ev = *(const float4*)&e[(size_t)k * DDIM + t * 4];
        double p = (double)zv.x * (double)ev.x + (double)zv.y * (double)ev.y
                 + (double)zv.z * (double)ev.z + (double)zv.w * (double)ev.w;
        #pragma unroll
        for (int o = 32; o > 0; o >>= 1) p += __shfl_down(p, o);
        dotf[c] = (float)p;   // correctly-rounded fp32 of exact dot
    }

    int bk = 0;
    if (t == 0) {
        #pragma clang fp contract(off)
        float sx = np_combine16(ch[w]);
        float bd = 3.4e38f;
        bk = 0x7fffffff;
        #pragma unroll
        for (int c = 0; c < 6; ++c) {
            float twod = 2.0f * dotf[c];
            float t1 = sx - twod;
            float d2v = t1 + e2np[bi[c]];
            d2v = fmaxf(d2v, 0.0f);
            float d = sqrtf(d2v);
            if (d < bd || (d == bd && bi[c] < bk)) { bd = d; bk = bi[c]; }
        }
    }
    int wk = __shfl(bk, 0);

    float4 ev = *(const float4*)&e[(size_t)wk * DDIM + t * 4];
    *(float4*)&out_zq[(size_t)n * DDIM + t * 4] = ev;
    float dx = zv.x - ev.x, dy = zv.y - ev.y, dz = zv.z - ev.z, dw = zv.w - ev.w;
    float sq = dx * dx + dy * dy + dz * dz + dw * dw;
    #pragma unroll
    for (int o = 32; o > 0; o >>= 1) sq += __shfl_down(sq, o);
    if (t == 0) {
        wsum[w] = sq;
        atomicAdd(&counts[wk], 1);
        out_idx[n] = (float)wk;
    }
    __syncthreads();
    if (threadIdx.x == 0)
        partials[blockIdx.x] = wsum[0] + wsum[1] + wsum[2] + wsum[3];
}

// ---------------- kernel 5: finalize loss ----------------
__global__ void finalize_kernel(const int* __restrict__ counts, const float* __restrict__ partials,
                                float* __restrict__ out_loss, int K, int NB,
                                float invN, float invND) {
    int t = threadIdx.x;
    double ent = 0.0, sq = 0.0;
    for (int k = t; k < K; k += 256) {
        float p = (float)counts[k] * invN;
        ent += (double)(p * logf(p + 1e-10f));
    }
    for (int i = t; i < NB; i += 256) sq += (double)partials[i];
    #pragma unroll
    for (int o = 32; o > 0; o >>= 1) {
        ent += __shfl_down(ent, o);
        sq  += __shfl_down(sq, o);
    }
    __shared__ double e4[4], s4[4];
    if ((t & 63) == 0) { e4[t >> 6] = ent; s4[t >> 6] = sq; }
    __syncthreads();
    if (t == 0) {
        double esum = e4[0] + e4[1] + e4[2] + e4[3];
        double ssum = s4[0] + s4[1] + s4[2] + s4[3];
        float perp = expf((float)(-esum));
        float mean = (float)ssum * invND;
        out_loss[0] = 1.25f * mean - 0.01f * perp;
    }
}

extern "C" void kernel_launch(void* const* d_in, const int* in_sizes, int n_in,
                              void* d_out, int out_size, void* d_ws, size_t ws_size,
                              hipStream_t stream) {
    const float* z = (const float*)d_in[0];
    const float* e = (const float*)d_in[1];
    const int N = in_sizes[0] / DDIM;   // 32768
    const int K = in_sizes[1] / DDIM;   // 2048

    float* out      = (float*)d_out;
    float* out_zq   = out;
    float* out_loss = out + (size_t)N * DDIM;
    float* out_idx  = out_loss + 1;

    // ws layout (bytes):
    //   counts[K]            @ 0        (8 KB)
    //   e2np[K]              @ 8192     (8 KB)
    //   partials[N/4]        @ 16384    (32 KB)
    //   cand_v[4][N][3] f32  @ 49152    (1.5 MB)
    //   cand_i[4][N][3] u16  @ 1622016  (768 KB)
    //   ebf_p (1 MB panels)  @ 2408448  -> total ~3.46 MB
    int*   counts   = (int*)d_ws;
    float* e2np     = (float*)((char*)d_ws + 8192);
    float* partials = (float*)((char*)d_ws + 16384);
    float* cand_v   = (float*)((char*)d_ws + 49152);
    u16*   cand_i   = (u16*)((char*)d_ws + 1622016);
    char*  ebf_p    = (char*)d_ws + 2408448;

    zero_counts_kernel<<<(K + 255) / 256, 256, 0, stream>>>(counts, K);
    code_norms_np_kernel<<<K, 64, 0, stream>>>(e, e2np);
    convert_permute_e_kernel<<<K * 32 / 256, 256, 0, stream>>>(e, ebf_p);
    vq_cand_kernel<<<dim3(N / ROWS_PER_BLOCK, NSPLIT), 256, 0, stream>>>(z, ebf_p, e2np,
                                                                         cand_v, cand_i, N);
    refine_fused_kernel<<<N / 4, 256, 0, stream>>>(z, e, e2np, cand_v, cand_i,
                                                   counts, partials, out_zq, out_idx, N);
    finalize_kernel<<<1, 256, 0, stream>>>(counts, partials, out_loss, K, N / 4,
                                           1.0f / (float)N, 1.0f / (float)(N * DDIM));
}